// Round 1
// baseline (552.677 us; speedup 1.0000x reference)
//
#include <hip/hip_runtime.h>

#define NB 8
#define CH 128
#define HH 160
#define WW 160
#define SPILL 40
#define LDS_ROWS 120   // rows [SPILL..159] live in LDS: 120*128*4 = 61440 B

// 9-tap conv along channel axis via wave shuffles. Thread t owns channels 2t, 2t+1.
// prev[2t-4..2t+5] gathered from lanes t-2..t+2. Zero-pad outside [0,128).
__device__ __forceinline__ float2 conv9(float2 p, const float* w, float b, int lane) {
    float m2x = __shfl_up(p.x, 2);  float m2y = __shfl_up(p.y, 2);
    float m1x = __shfl_up(p.x, 1);  float m1y = __shfl_up(p.y, 1);
    float p1x = __shfl_down(p.x, 1); float p1y = __shfl_down(p.y, 1);
    float p2x = __shfl_down(p.x, 2); float p2y = __shfl_down(p.y, 2);
    if (lane < 2)  { m2x = 0.f; m2y = 0.f; }
    if (lane < 1)  { m1x = 0.f; m1y = 0.f; }
    if (lane > 62) { p1x = 0.f; p1y = 0.f; }
    if (lane > 61) { p2x = 0.f; p2y = 0.f; }
    // e[0..9] = prev[2t-4 .. 2t+5]
    float e0=m2x,e1=m2y,e2=m1x,e3=m1y,e4=p.x,e5=p.y,e6=p1x,e7=p1y,e8=p2x,e9=p2y;
    // y[c] = b + sum_j w[j]*prev[c-4+j]  (cross-correlation). Two-acc tree per output.
    float ax = fmaf(w[0], e0, b);
    ax = fmaf(w[2], e2, ax); ax = fmaf(w[4], e4, ax);
    ax = fmaf(w[6], e6, ax); ax = fmaf(w[8], e8, ax);
    float bx = w[1]*e1; bx = fmaf(w[3], e3, bx);
    bx = fmaf(w[5], e5, bx); bx = fmaf(w[7], e7, bx);
    float ay = fmaf(w[0], e1, b);
    ay = fmaf(w[2], e3, ay); ay = fmaf(w[4], e5, ay);
    ay = fmaf(w[6], e7, ay); ay = fmaf(w[8], e9, ay);
    float by = w[1]*e2; by = fmaf(w[3], e4, by);
    by = fmaf(w[5], e6, by); by = fmaf(w[7], e8, by);
    return make_float2(ax + bx, ay + by);
}

// K0: NCHW -> NHWC. x[n][c][p] -> A[n][p][c], p = h*W+w (P = 25600).
__global__ __launch_bounds__(256) void k0_transpose(const float* __restrict__ x,
                                                    float* __restrict__ A) {
    __shared__ float t[32][33];
    int p0 = blockIdx.x * 32;
    int c0 = blockIdx.y * 32;
    int n  = blockIdx.z;
    int tx = threadIdx.x, ty = threadIdx.y;
    const float* xn = x + (size_t)n * CH * HH * WW;
    float* An = A + (size_t)n * HH * WW * CH;
    #pragma unroll
    for (int k = 0; k < 4; k++)
        t[ty + 8*k][tx] = xn[(size_t)(c0 + ty + 8*k) * (HH*WW) + p0 + tx];
    __syncthreads();
    #pragma unroll
    for (int k = 0; k < 4; k++)
        An[(size_t)(p0 + ty + 8*k) * CH + c0 + tx] = t[tx][ty + 8*k];
}

// K1: fused down+up scan over H, in-place on A. Block = 1 wave per (n,w) column.
__global__ __launch_bounds__(64) void k1_vert(float* __restrict__ A,
        const float* __restrict__ wdp, const float* __restrict__ bdp,
        const float* __restrict__ wup, const float* __restrict__ bup) {
    __shared__ float lds[LDS_ROWS][CH];   // relu(d) rows SPILL..159, x/y split to avoid 4-way bank conflicts
    int lane = threadIdx.x;
    int w = blockIdx.x, n = blockIdx.y;
    float wd[9], wu[9];
    #pragma unroll
    for (int j = 0; j < 9; j++) { wd[j] = wdp[j]; wu[j] = wup[j]; }
    float bd = bdp[0], bu = bup[0];
    float* col = A + ((size_t)n * HH * WW + w) * CH + 2*lane;
    const size_t RS = (size_t)WW * CH;  // row stride (floats)

    // ---- down scan: d[h] = relu(conv(d[h-1], wd)+bd) + x[h]; d[0] = x[0] ----
    float2 d;
    float2 qf[8];
    #pragma unroll
    for (int i = 0; i < 8; i++) qf[i] = *(const float2*)(col + (size_t)i * RS);
    for (int hb = 0; hb < HH; hb += 8) {
        #pragma unroll
        for (int k = 0; k < 8; k++) {
            int h = hb + k;
            float2 xr = qf[k];
            if (h + 8 < HH) qf[k] = *(const float2*)(col + (size_t)(h+8) * RS);
            if (h == 0) d = xr;
            else {
                float2 cv = conv9(d, wd, bd, lane);
                d.x = fmaxf(cv.x, 0.f) + xr.x;
                d.y = fmaxf(cv.y, 0.f) + xr.y;
            }
            float rx = fmaxf(d.x, 0.f), ry = fmaxf(d.y, 0.f);
            if (h < SPILL) *(float2*)(col + (size_t)h * RS) = make_float2(rx, ry);
            else { lds[h-SPILL][lane] = rx; lds[h-SPILL][64+lane] = ry; }
        }
    }

    // ---- up scan: u[s] = relu(conv(u[s-1], wu)+bu) + relu(d[159-s]); u[0] = relu(d[159]) ----
    float2 u;
    float2 pf0 = {0,0}, pf1 = {0,0}, pf2 = {0,0}, pf3 = {0,0};
    #pragma unroll 8
    for (int s = 0; s < HH; s++) {
        int h = HH - 1 - s;
        float2 t2;
        if (h >= SPILL) { t2.x = lds[h-SPILL][lane]; t2.y = lds[h-SPILL][64+lane]; }
        else t2 = pf0;
        pf0 = pf1; pf1 = pf2; pf2 = pf3;
        int hq = h - 4;
        if (hq >= 0 && hq < SPILL) pf3 = *(const float2*)(col + (size_t)hq * RS);
        if (s == 0) u = t2;
        else {
            float2 cv = conv9(u, wu, bu, lane);
            u.x = fmaxf(cv.x, 0.f) + t2.x;
            u.y = fmaxf(cv.y, 0.f) + t2.y;
        }
        *(float2*)(col + (size_t)h * RS) = u;   // A[n][h][w][c] = u[n][159-h][w][c]
    }
}

// K2: fused left+right scan over W, in-place on A. Block = 1 wave per (n, h_phys) row-plane.
__global__ __launch_bounds__(64) void k2_horz(float* __restrict__ A,
        const float* __restrict__ wlp, const float* __restrict__ blp,
        const float* __restrict__ wrp, const float* __restrict__ brp) {
    __shared__ float lds[LDS_ROWS][CH];
    int lane = threadIdx.x;
    int hp = blockIdx.x, n = blockIdx.y;
    float wl[9], wr[9];
    #pragma unroll
    for (int j = 0; j < 9; j++) { wl[j] = wlp[j]; wr[j] = wrp[j]; }
    float bl = blp[0], br = brp[0];
    float* row0 = A + ((size_t)n * HH + hp) * WW * CH + 2*lane;
    const size_t PS = CH;  // step stride along w (floats)

    // ---- left scan: l[a] = relu(conv(l[a-1], wl)+bl) + relu(A[hp][a]); l[0] = relu(A[hp][0]) ----
    float2 l;
    float2 qf[8];
    #pragma unroll
    for (int i = 0; i < 8; i++) qf[i] = *(const float2*)(row0 + (size_t)i * PS);
    for (int ab = 0; ab < WW; ab += 8) {
        #pragma unroll
        for (int k = 0; k < 8; k++) {
            int a = ab + k;
            float2 xr = qf[k];
            if (a + 8 < WW) qf[k] = *(const float2*)(row0 + (size_t)(a+8) * PS);
            xr.x = fmaxf(xr.x, 0.f); xr.y = fmaxf(xr.y, 0.f);
            if (a == 0) l = xr;
            else {
                float2 cv = conv9(l, wl, bl, lane);
                l.x = fmaxf(cv.x, 0.f) + xr.x;
                l.y = fmaxf(cv.y, 0.f) + xr.y;
            }
            float rx = fmaxf(l.x, 0.f), ry = fmaxf(l.y, 0.f);
            if (a < SPILL) *(float2*)(row0 + (size_t)a * PS) = make_float2(rx, ry);
            else { lds[a-SPILL][lane] = rx; lds[a-SPILL][64+lane] = ry; }
        }
    }

    // ---- right scan: r[s] = relu(conv(r[s-1], wr)+br) + relu(l[159-s]); r[0] = relu(l[159]) ----
    float2 r;
    float2 pf0 = {0,0}, pf1 = {0,0}, pf2 = {0,0}, pf3 = {0,0};
    #pragma unroll 8
    for (int s = 0; s < WW; s++) {
        int a = WW - 1 - s;
        float2 t6;
        if (a >= SPILL) { t6.x = lds[a-SPILL][lane]; t6.y = lds[a-SPILL][64+lane]; }
        else t6 = pf0;
        pf0 = pf1; pf1 = pf2; pf2 = pf3;
        int aq = a - 4;
        if (aq >= 0 && aq < SPILL) pf3 = *(const float2*)(row0 + (size_t)aq * PS);
        if (s == 0) r = t6;
        else {
            float2 cv = conv9(r, wr, br, lane);
            r.x = fmaxf(cv.x, 0.f) + t6.x;
            r.y = fmaxf(cv.y, 0.f) + t6.y;
        }
        *(float2*)(row0 + (size_t)a * PS) = r;  // A[n][hp][p][c] = r[n][159-p][159-hp][c]
    }
}

// K3: out[n][c][159-h][159-w] = relu(A[n][h][w][c])  (NHWC -> NCHW + flips + final relu)
__global__ __launch_bounds__(256) void k3_out(const float* __restrict__ A,
                                              float* __restrict__ out) {
    __shared__ float t[32][33];
    int w0 = blockIdx.x * 32;     // 5 tiles
    int c0 = blockIdx.y * 32;     // 4 tiles
    int nh = blockIdx.z;          // n*H + h
    int n = nh / HH, h = nh % HH;
    const float* Ap = A + (size_t)nh * WW * CH;
    int tx = threadIdx.x, ty = threadIdx.y;
    #pragma unroll
    for (int k = 0; k < 4; k++)
        t[ty + 8*k][tx] = Ap[(size_t)(w0 + ty + 8*k) * CH + c0 + tx];
    __syncthreads();
    int ho = HH - 1 - h;
    #pragma unroll
    for (int k = 0; k < 4; k++) {
        int c = c0 + ty + 8*k;
        float v = t[tx][ty + 8*k];
        out[((size_t)(n * CH + c) * HH + ho) * WW + (WW - 1 - (w0 + tx))] = fmaxf(v, 0.f);
    }
}

extern "C" void kernel_launch(void* const* d_in, const int* in_sizes, int n_in,
                              void* d_out, int out_size, void* d_ws, size_t ws_size,
                              hipStream_t stream) {
    (void)in_sizes; (void)n_in; (void)out_size; (void)ws_size;
    const float* x  = (const float*)d_in[0];
    const float* wd = (const float*)d_in[1];
    const float* bd = (const float*)d_in[2];
    const float* wu = (const float*)d_in[3];
    const float* bu = (const float*)d_in[4];
    const float* wl = (const float*)d_in[5];
    const float* bl = (const float*)d_in[6];
    const float* wr = (const float*)d_in[7];
    const float* br = (const float*)d_in[8];
    float* out = (float*)d_out;
    float* A   = (float*)d_ws;   // needs N*H*W*C*4 = 104,857,600 bytes

    dim3 g0(HH*WW/32, CH/32, NB), b0(32, 8);
    k0_transpose<<<g0, b0, 0, stream>>>(x, A);

    dim3 g1(WW, NB), b1(64);
    k1_vert<<<g1, b1, 0, stream>>>(A, wd, bd, wu, bu);

    dim3 g2(HH, NB);
    k2_horz<<<g2, b1, 0, stream>>>(A, wl, bl, wr, br);

    dim3 g3(WW/32, CH/32, NB*HH), b3(32, 8);
    k3_out<<<g3, b3, 0, stream>>>(A, out);
}

// Round 2
// 518.644 us; speedup vs baseline: 1.0656x; 1.0656x over previous
//
#include <hip/hip_runtime.h>

#define NB 8
#define CH 128
#define HH 160
#define WW 160
#define SPILL 40
#define LDS_ROWS 120   // rows [SPILL..159] live in LDS: 120*128*4 = 61440 B -> 2 blocks/CU

// DPP full-wave shifts (CDNA keeps wave_* DPP). bound_ctrl=1 -> out-of-wave source reads 0,
// which IS the channel zero-padding. wave_shr:1 = 0x138 (lane i reads i-1),
// wave_shl:1 = 0x130 (lane i reads i+1).
__device__ __forceinline__ float dpp_up1(float x) {   // lane i <- lane i-1, lane 0 <- 0
    return __int_as_float(__builtin_amdgcn_update_dpp(0, __float_as_int(x), 0x138, 0xF, 0xF, true));
}
__device__ __forceinline__ float dpp_dn1(float x) {   // lane i <- lane i+1, lane 63 <- 0
    return __int_as_float(__builtin_amdgcn_update_dpp(0, __float_as_int(x), 0x130, 0xF, 0xF, true));
}

// 9-tap conv along channel axis. Thread t owns channels 2t, 2t+1.
// e[0..9] = prev[2t-4 .. 2t+5]; zero-pad outside [0,128) via DPP bound_ctrl.
__device__ __forceinline__ float2 conv9(float2 p, const float* w, float b) {
    float m1x = dpp_up1(p.x), m1y = dpp_up1(p.y);   // prev[2t-2], prev[2t-1]
    float m2x = dpp_up1(m1x), m2y = dpp_up1(m1y);   // prev[2t-4], prev[2t-3]
    float p1x = dpp_dn1(p.x), p1y = dpp_dn1(p.y);   // prev[2t+2], prev[2t+3]
    float p2x = dpp_dn1(p1x), p2y = dpp_dn1(p1y);   // prev[2t+4], prev[2t+5]
    float e0=m2x,e1=m2y,e2=m1x,e3=m1y,e4=p.x,e5=p.y,e6=p1x,e7=p1y,e8=p2x,e9=p2y;
    // y[c] = b + sum_j w[j]*prev[c-4+j]; two-accumulator trees per output.
    float ax = fmaf(w[0], e0, b);
    ax = fmaf(w[2], e2, ax); ax = fmaf(w[4], e4, ax);
    ax = fmaf(w[6], e6, ax); ax = fmaf(w[8], e8, ax);
    float bx = w[1]*e1; bx = fmaf(w[3], e3, bx);
    bx = fmaf(w[5], e5, bx); bx = fmaf(w[7], e7, bx);
    float ay = fmaf(w[0], e1, b);
    ay = fmaf(w[2], e3, ay); ay = fmaf(w[4], e5, ay);
    ay = fmaf(w[6], e7, ay); ay = fmaf(w[8], e9, ay);
    float by = w[1]*e2; by = fmaf(w[3], e4, by);
    by = fmaf(w[5], e6, by); by = fmaf(w[7], e8, by);
    return make_float2(ax + bx, ay + by);
}

// K0: NCHW -> NHWC. x[n][c][p] -> A[n][p][c], p = h*W+w.
__global__ __launch_bounds__(256) void k0_transpose(const float* __restrict__ x,
                                                    float* __restrict__ A) {
    __shared__ float t[32][33];
    int p0 = blockIdx.x * 32;
    int c0 = blockIdx.y * 32;
    int n  = blockIdx.z;
    int tx = threadIdx.x, ty = threadIdx.y;
    const float* xn = x + (size_t)n * CH * HH * WW;
    float* An = A + (size_t)n * HH * WW * CH;
    #pragma unroll
    for (int k = 0; k < 4; k++)
        t[ty + 8*k][tx] = xn[(size_t)(c0 + ty + 8*k) * (HH*WW) + p0 + tx];
    __syncthreads();
    #pragma unroll
    for (int k = 0; k < 4; k++)
        An[(size_t)(p0 + ty + 8*k) * CH + c0 + tx] = t[tx][ty + 8*k];
}

// K1: fused down+up scan over H, in-place on A. Block = 1 wave per (n,w) column.
__global__ __launch_bounds__(64) void k1_vert(float* __restrict__ A,
        const float* __restrict__ wdp, const float* __restrict__ bdp,
        const float* __restrict__ wup, const float* __restrict__ bup) {
    __shared__ float lds[LDS_ROWS][CH];   // relu(d), x in [..][lane], y in [..][64+lane]
    int lane = threadIdx.x;
    int w = blockIdx.x, n = blockIdx.y;
    float wd[9], wu[9];
    #pragma unroll
    for (int j = 0; j < 9; j++) { wd[j] = wdp[j]; wu[j] = wup[j]; }
    float bd = bdp[0], bu = bup[0];
    float* col = A + ((size_t)n * HH * WW + w) * CH + 2*lane;
    const size_t RS = (size_t)WW * CH;  // row stride (floats)

    // ---- down scan: d[h] = relu(conv(d[h-1], wd)+bd) + x[h]; d[0] = x[0] ----
    float2 d;
    float2 qf[16];                      // 16-deep global prefetch ring (8 KB in flight)
    #pragma unroll
    for (int i = 0; i < 16; i++) qf[i] = *(const float2*)(col + (size_t)i * RS);
    for (int hb = 0; hb < HH; hb += 16) {
        #pragma unroll
        for (int k = 0; k < 16; k++) {
            int h = hb + k;
            float2 xr = qf[k];
            if (h + 16 < HH) qf[k] = *(const float2*)(col + (size_t)(h+16) * RS);
            if (h == 0) d = xr;
            else {
                float2 cv = conv9(d, wd, bd);
                d.x = fmaxf(cv.x, 0.f) + xr.x;
                d.y = fmaxf(cv.y, 0.f) + xr.y;
            }
            float rx = fmaxf(d.x, 0.f), ry = fmaxf(d.y, 0.f);
            if (h < SPILL) *(float2*)(col + (size_t)h * RS) = make_float2(rx, ry);
            else { lds[h-SPILL][lane] = rx; lds[h-SPILL][64+lane] = ry; }
        }
    }

    // ---- up scan: u[s] = relu(conv(u[s-1], wu)+bu) + relu(d[159-s]); u[0] = relu(d[159]) ----
    // Unified 8-deep ring tf[] prefetching relu(d) rows from LDS or global spill.
    float2 u;
    float2 tf[8];
    #pragma unroll
    for (int k = 0; k < 8; k++) {
        int h = HH - 1 - k;            // 159..152, all >= SPILL
        tf[k] = make_float2(lds[h-SPILL][lane], lds[h-SPILL][64+lane]);
    }
    for (int sb = 0; sb < HH; sb += 8) {
        #pragma unroll
        for (int k = 0; k < 8; k++) {
            int s = sb + k;
            int h = HH - 1 - s;
            float2 t2 = tf[k];
            int h2 = h - 8;
            if (h2 >= SPILL)      tf[k] = make_float2(lds[h2-SPILL][lane], lds[h2-SPILL][64+lane]);
            else if (h2 >= 0)     tf[k] = *(const float2*)(col + (size_t)h2 * RS);
            if (s == 0) u = t2;
            else {
                float2 cv = conv9(u, wu, bu);
                u.x = fmaxf(cv.x, 0.f) + t2.x;
                u.y = fmaxf(cv.y, 0.f) + t2.y;
            }
            *(float2*)(col + (size_t)h * RS) = u;   // A[n][h][w][c] = u[n][159-h][w][c]
        }
    }
}

// K2: fused left+right scan over W, in-place on A. Block = 1 wave per (n, h_phys) row.
__global__ __launch_bounds__(64) void k2_horz(float* __restrict__ A,
        const float* __restrict__ wlp, const float* __restrict__ blp,
        const float* __restrict__ wrp, const float* __restrict__ brp) {
    __shared__ float lds[LDS_ROWS][CH];
    int lane = threadIdx.x;
    int hp = blockIdx.x, n = blockIdx.y;
    float wl[9], wr[9];
    #pragma unroll
    for (int j = 0; j < 9; j++) { wl[j] = wlp[j]; wr[j] = wrp[j]; }
    float bl = blp[0], br = brp[0];
    float* row0 = A + ((size_t)n * HH + hp) * WW * CH + 2*lane;
    const size_t PS = CH;  // step stride along w (floats)

    // ---- left scan: l[a] = relu(conv(l[a-1], wl)+bl) + relu(A[hp][a]); l[0] = relu(A[hp][0]) ----
    float2 l;
    float2 qf[16];
    #pragma unroll
    for (int i = 0; i < 16; i++) qf[i] = *(const float2*)(row0 + (size_t)i * PS);
    for (int ab = 0; ab < WW; ab += 16) {
        #pragma unroll
        for (int k = 0; k < 16; k++) {
            int a = ab + k;
            float2 xr = qf[k];
            if (a + 16 < WW) qf[k] = *(const float2*)(row0 + (size_t)(a+16) * PS);
            xr.x = fmaxf(xr.x, 0.f); xr.y = fmaxf(xr.y, 0.f);
            if (a == 0) l = xr;
            else {
                float2 cv = conv9(l, wl, bl);
                l.x = fmaxf(cv.x, 0.f) + xr.x;
                l.y = fmaxf(cv.y, 0.f) + xr.y;
            }
            float rx = fmaxf(l.x, 0.f), ry = fmaxf(l.y, 0.f);
            if (a < SPILL) *(float2*)(row0 + (size_t)a * PS) = make_float2(rx, ry);
            else { lds[a-SPILL][lane] = rx; lds[a-SPILL][64+lane] = ry; }
        }
    }

    // ---- right scan: r[s] = relu(conv(r[s-1], wr)+br) + relu(l[159-s]); r[0] = relu(l[159]) ----
    float2 r;
    float2 tf[8];
    #pragma unroll
    for (int k = 0; k < 8; k++) {
        int a = WW - 1 - k;
        tf[k] = make_float2(lds[a-SPILL][lane], lds[a-SPILL][64+lane]);
    }
    for (int sb = 0; sb < WW; sb += 8) {
        #pragma unroll
        for (int k = 0; k < 8; k++) {
            int s = sb + k;
            int a = WW - 1 - s;
            float2 t6 = tf[k];
            int a2 = a - 8;
            if (a2 >= SPILL)      tf[k] = make_float2(lds[a2-SPILL][lane], lds[a2-SPILL][64+lane]);
            else if (a2 >= 0)     tf[k] = *(const float2*)(row0 + (size_t)a2 * PS);
            if (s == 0) r = t6;
            else {
                float2 cv = conv9(r, wr, br);
                r.x = fmaxf(cv.x, 0.f) + t6.x;
                r.y = fmaxf(cv.y, 0.f) + t6.y;
            }
            *(float2*)(row0 + (size_t)a * PS) = r;  // A[n][hp][p][c] = r[n][159-p][159-hp][c]
        }
    }
}

// K3: out[n][c][159-h][159-w] = relu(A[n][h][w][c])  (NHWC -> NCHW + flips + final relu)
__global__ __launch_bounds__(256) void k3_out(const float* __restrict__ A,
                                              float* __restrict__ out) {
    __shared__ float t[32][33];
    int w0 = blockIdx.x * 32;
    int c0 = blockIdx.y * 32;
    int nh = blockIdx.z;
    int n = nh / HH, h = nh % HH;
    const float* Ap = A + (size_t)nh * WW * CH;
    int tx = threadIdx.x, ty = threadIdx.y;
    #pragma unroll
    for (int k = 0; k < 4; k++)
        t[ty + 8*k][tx] = Ap[(size_t)(w0 + ty + 8*k) * CH + c0 + tx];
    __syncthreads();
    int ho = HH - 1 - h;
    #pragma unroll
    for (int k = 0; k < 4; k++) {
        int c = c0 + ty + 8*k;
        float v = t[tx][ty + 8*k];
        out[((size_t)(n * CH + c) * HH + ho) * WW + (WW - 1 - (w0 + tx))] = fmaxf(v, 0.f);
    }
}

extern "C" void kernel_launch(void* const* d_in, const int* in_sizes, int n_in,
                              void* d_out, int out_size, void* d_ws, size_t ws_size,
                              hipStream_t stream) {
    (void)in_sizes; (void)n_in; (void)out_size; (void)ws_size;
    const float* x  = (const float*)d_in[0];
    const float* wd = (const float*)d_in[1];
    const float* bd = (const float*)d_in[2];
    const float* wu = (const float*)d_in[3];
    const float* bu = (const float*)d_in[4];
    const float* wl = (const float*)d_in[5];
    const float* bl = (const float*)d_in[6];
    const float* wr = (const float*)d_in[7];
    const float* br = (const float*)d_in[8];
    float* out = (float*)d_out;
    float* A   = (float*)d_ws;   // needs N*H*W*C*4 = 104,857,600 bytes

    dim3 g0(HH*WW/32, CH/32, NB), b0(32, 8);
    k0_transpose<<<g0, b0, 0, stream>>>(x, A);

    dim3 g1(WW, NB), b1(64);
    k1_vert<<<g1, b1, 0, stream>>>(A, wd, bd, wu, bu);

    dim3 g2(HH, NB);
    k2_horz<<<g2, b1, 0, stream>>>(A, wl, bl, wr, br);

    dim3 g3(WW/32, CH/32, NB*HH), b3(32, 8);
    k3_out<<<g3, b3, 0, stream>>>(A, out);
}

// Round 3
// 363.431 us; speedup vs baseline: 1.5207x; 1.4271x over previous
//
#include <hip/hip_runtime.h>

#define NB 8
#define CH 128
#define HH 160
#define WW 160
#define SPILL 100
#define LDS_ROWS 60   // rows [SPILL..159] in LDS: 60*128*4 = 30720 B -> 5 blocks/CU (exactly full grid resident)

// DPP full-wave shifts; bound_ctrl=1 zero-fills out-of-wave = channel zero-padding.
__device__ __forceinline__ float dpp_up1(float x) {   // lane i <- lane i-1, lane 0 <- 0
    return __int_as_float(__builtin_amdgcn_update_dpp(0, __float_as_int(x), 0x138, 0xF, 0xF, true));
}
__device__ __forceinline__ float dpp_dn1(float x) {   // lane i <- lane i+1, lane 63 <- 0
    return __int_as_float(__builtin_amdgcn_update_dpp(0, __float_as_int(x), 0x130, 0xF, 0xF, true));
}

// 9-tap conv along channels; thread t owns channels 2t,2t+1. 3x3-tap trees (chain: 3 fma + 2 add).
__device__ __forceinline__ float2 conv9(float2 p, const float* w, float b) {
    float m1x = dpp_up1(p.x), m1y = dpp_up1(p.y);
    float m2x = dpp_up1(m1x), m2y = dpp_up1(m1y);
    float p1x = dpp_dn1(p.x), p1y = dpp_dn1(p.y);
    float p2x = dpp_dn1(p1x), p2y = dpp_dn1(p1y);
    float e0=m2x,e1=m2y,e2=m1x,e3=m1y,e4=p.x,e5=p.y,e6=p1x,e7=p1y,e8=p2x,e9=p2y;
    float ax = fmaf(w[0], e0, b);       ax = fmaf(w[3], e3, ax); ax = fmaf(w[6], e6, ax);
    float bx = w[1]*e1;                 bx = fmaf(w[4], e4, bx); bx = fmaf(w[7], e7, bx);
    float cx = w[2]*e2;                 cx = fmaf(w[5], e5, cx); cx = fmaf(w[8], e8, cx);
    float ay = fmaf(w[0], e1, b);       ay = fmaf(w[3], e4, ay); ay = fmaf(w[6], e7, ay);
    float by = w[1]*e2;                 by = fmaf(w[4], e5, by); by = fmaf(w[7], e8, by);
    float cy = w[2]*e3;                 cy = fmaf(w[5], e6, cy); cy = fmaf(w[8], e9, cy);
    return make_float2((ax + bx) + cx, (ay + by) + cy);
}

// K0: NCHW -> NHWC. Tile: 32 c x 128 p. Reads float4 (512B/row), writes float2 (128B segs).
__global__ __launch_bounds__(256) void k0_transpose(const float* __restrict__ x,
                                                    float* __restrict__ A) {
    __shared__ float t[32][132];   // 132: float4-aligned row, breaks worst banking
    int p0 = blockIdx.x * 128;
    int c0 = blockIdx.y * 32;
    int n  = blockIdx.z;
    int tid = threadIdx.x;
    const float* xn = x + (size_t)n * CH * HH * WW;
    float* An = A + (size_t)n * HH * WW * CH;
    #pragma unroll
    for (int j = 0; j < 4; j++) {
        int c = j*8 + tid/32;
        int q4 = (tid%32)*4;
        float4 v = *(const float4*)(xn + (size_t)(c0 + c) * (HH*WW) + p0 + q4);
        *(float4*)&t[c][q4] = v;
    }
    __syncthreads();
    #pragma unroll
    for (int j = 0; j < 8; j++) {
        int p  = j*16 + tid/16;
        int cq = (tid%16)*2;
        float2 v = make_float2(t[cq][p], t[cq+1][p]);
        *(float2*)(An + (size_t)(p0 + p) * CH + c0 + cq) = v;
    }
}

// K1: fused down+up scan over H, in-place on A. 1 wave per (n,w) column; 5 blocks/CU.
__global__ __launch_bounds__(64) void k1_vert(float* __restrict__ A,
        const float* __restrict__ wdp, const float* __restrict__ bdp,
        const float* __restrict__ wup, const float* __restrict__ bup) {
    __shared__ float lds[LDS_ROWS][CH];   // relu(d) rows SPILL..159; x at [r][lane], y at [r][64+lane] (2-way = free)
    int lane = threadIdx.x;
    int w = blockIdx.x, n = blockIdx.y;
    float wd[9], wu[9];
    #pragma unroll
    for (int j = 0; j < 9; j++) { wd[j] = wdp[j]; wu[j] = wup[j]; }
    float bd = bdp[0], bu = bup[0];
    float* col = A + ((size_t)n * HH * WW + w) * CH + 2*lane;
    const size_t RS = (size_t)WW * CH;

    // ---- down: d[h] = relu(conv(d[h-1]))+x[h]; rows <SPILL spill relu(d) in-place, rest to LDS ----
    float2 d;
    float2 qf[16];
    #pragma unroll
    for (int i = 0; i < 16; i++) qf[i] = *(const float2*)(col + (size_t)i * RS);
    for (int hb = 0; hb < HH; hb += 16) {
        #pragma unroll
        for (int k = 0; k < 16; k++) {
            int h = hb + k;
            float2 xr = qf[k];
            if (h + 16 < HH) qf[k] = *(const float2*)(col + (size_t)(h+16) * RS);
            if (h == 0) d = xr;
            else {
                float2 cv = conv9(d, wd, bd);
                d.x = fmaxf(cv.x, 0.f) + xr.x;
                d.y = fmaxf(cv.y, 0.f) + xr.y;
            }
            float rx = fmaxf(d.x, 0.f), ry = fmaxf(d.y, 0.f);
            if (h < SPILL) *(float2*)(col + (size_t)h * RS) = make_float2(rx, ry);
            else { lds[h-SPILL][lane] = rx; lds[h-SPILL][64+lane] = ry; }
        }
    }

    // ---- up: u[s] = relu(conv(u[s-1]))+relu(d[159-s]); 8-deep mixed LDS/global ring ----
    float2 u;
    float2 tf[8];
    #pragma unroll
    for (int k = 0; k < 8; k++) {
        int h = HH - 1 - k;   // 159..152, all >= SPILL
        tf[k] = make_float2(lds[h-SPILL][lane], lds[h-SPILL][64+lane]);
    }
    for (int sb = 0; sb < HH; sb += 8) {
        #pragma unroll
        for (int k = 0; k < 8; k++) {
            int s = sb + k;
            int h = HH - 1 - s;
            float2 t2 = tf[k];
            int h2 = h - 8;
            if (h2 >= SPILL)    tf[k] = make_float2(lds[h2-SPILL][lane], lds[h2-SPILL][64+lane]);
            else if (h2 >= 0)   tf[k] = *(const float2*)(col + (size_t)h2 * RS);
            if (s == 0) u = t2;
            else {
                float2 cv = conv9(u, wu, bu);
                u.x = fmaxf(cv.x, 0.f) + t2.x;
                u.y = fmaxf(cv.y, 0.f) + t2.y;
            }
            *(float2*)(col + (size_t)h * RS) = u;
        }
    }
}

// K2: fused left+right scan over W, in-place on A. 1 wave per (n,h) row; 5 blocks/CU.
__global__ __launch_bounds__(64) void k2_horz(float* __restrict__ A,
        const float* __restrict__ wlp, const float* __restrict__ blp,
        const float* __restrict__ wrp, const float* __restrict__ brp) {
    __shared__ float lds[LDS_ROWS][CH];
    int lane = threadIdx.x;
    int hp = blockIdx.x, n = blockIdx.y;
    float wl[9], wr[9];
    #pragma unroll
    for (int j = 0; j < 9; j++) { wl[j] = wlp[j]; wr[j] = wrp[j]; }
    float bl = blp[0], br = brp[0];
    float* row0 = A + ((size_t)n * HH + hp) * WW * CH + 2*lane;
    const size_t PS = CH;

    float2 l;
    float2 qf[16];
    #pragma unroll
    for (int i = 0; i < 16; i++) qf[i] = *(const float2*)(row0 + (size_t)i * PS);
    for (int ab = 0; ab < WW; ab += 16) {
        #pragma unroll
        for (int k = 0; k < 16; k++) {
            int a = ab + k;
            float2 xr = qf[k];
            if (a + 16 < WW) qf[k] = *(const float2*)(row0 + (size_t)(a+16) * PS);
            xr.x = fmaxf(xr.x, 0.f); xr.y = fmaxf(xr.y, 0.f);
            if (a == 0) l = xr;
            else {
                float2 cv = conv9(l, wl, bl);
                l.x = fmaxf(cv.x, 0.f) + xr.x;
                l.y = fmaxf(cv.y, 0.f) + xr.y;
            }
            float rx = fmaxf(l.x, 0.f), ry = fmaxf(l.y, 0.f);
            if (a < SPILL) *(float2*)(row0 + (size_t)a * PS) = make_float2(rx, ry);
            else { lds[a-SPILL][lane] = rx; lds[a-SPILL][64+lane] = ry; }
        }
    }

    float2 r;
    float2 tf[8];
    #pragma unroll
    for (int k = 0; k < 8; k++) {
        int a = WW - 1 - k;
        tf[k] = make_float2(lds[a-SPILL][lane], lds[a-SPILL][64+lane]);
    }
    for (int sb = 0; sb < WW; sb += 8) {
        #pragma unroll
        for (int k = 0; k < 8; k++) {
            int s = sb + k;
            int a = WW - 1 - s;
            float2 t6 = tf[k];
            int a2 = a - 8;
            if (a2 >= SPILL)    tf[k] = make_float2(lds[a2-SPILL][lane], lds[a2-SPILL][64+lane]);
            else if (a2 >= 0)   tf[k] = *(const float2*)(row0 + (size_t)a2 * PS);
            if (s == 0) r = t6;
            else {
                float2 cv = conv9(r, wr, br);
                r.x = fmaxf(cv.x, 0.f) + t6.x;
                r.y = fmaxf(cv.y, 0.f) + t6.y;
            }
            *(float2*)(row0 + (size_t)a * PS) = r;
        }
    }
}

// K3: out[n][c][159-h][159-w] = relu(A[n][h][w][c]). Tile: 32 w x 128 c per (n,h).
__global__ __launch_bounds__(256) void k3_out(const float* __restrict__ A,
                                              float* __restrict__ out) {
    __shared__ float t[32][132];
    int w0 = blockIdx.x * 32;     // 5 tiles
    int nh = blockIdx.y;          // n*HH + h
    int n = nh / HH, h = nh % HH;
    const float* Ap = A + (size_t)nh * WW * CH;
    int tid = threadIdx.x;
    #pragma unroll
    for (int j = 0; j < 4; j++) {
        int wl = j*8 + tid/32;
        int c4 = (tid%32)*4;
        float4 v = *(const float4*)(Ap + (size_t)(w0 + wl) * CH + c4);
        v.x = fmaxf(v.x, 0.f); v.y = fmaxf(v.y, 0.f);
        v.z = fmaxf(v.z, 0.f); v.w = fmaxf(v.w, 0.f);
        *(float4*)&t[wl][c4] = v;
    }
    __syncthreads();
    int ho = HH - 1 - h;
    #pragma unroll
    for (int j = 0; j < 16; j++) {
        int c  = j*8 + tid/32;
        int wl = tid%32;
        out[((size_t)(n * CH + c) * HH + ho) * WW + (WW - 1 - (w0 + wl))] = t[wl][c];
    }
}

extern "C" void kernel_launch(void* const* d_in, const int* in_sizes, int n_in,
                              void* d_out, int out_size, void* d_ws, size_t ws_size,
                              hipStream_t stream) {
    (void)in_sizes; (void)n_in; (void)out_size; (void)ws_size;
    const float* x  = (const float*)d_in[0];
    const float* wd = (const float*)d_in[1];
    const float* bd = (const float*)d_in[2];
    const float* wu = (const float*)d_in[3];
    const float* bu = (const float*)d_in[4];
    const float* wl = (const float*)d_in[5];
    const float* bl = (const float*)d_in[6];
    const float* wr = (const float*)d_in[7];
    const float* br = (const float*)d_in[8];
    float* out = (float*)d_out;
    float* A   = (float*)d_ws;   // needs N*H*W*C*4 = 104,857,600 bytes

    dim3 g0(HH*WW/128, CH/32, NB), b0(256);
    k0_transpose<<<g0, b0, 0, stream>>>(x, A);

    dim3 g1(WW, NB), b1(64);
    k1_vert<<<g1, b1, 0, stream>>>(A, wd, bd, wu, bu);

    dim3 g2(HH, NB);
    k2_horz<<<g2, b1, 0, stream>>>(A, wl, bl, wr, br);

    dim3 g3(WW/32, NB*HH), b3(256);
    k3_out<<<g3, b3, 0, stream>>>(A, out);
}